// Round 13
// baseline (1023.036 us; speedup 1.0000x reference)
//
#include <hip/hip_runtime.h>
#include <hip/hip_cooperative_groups.h>

#define NN 100000
#define NE 600000
#define DD 128
#define NG 512
#define NC 10
#define NL 4

namespace cg = cooperative_groups;

typedef __attribute__((ext_vector_type(8))) short short8;
typedef __attribute__((ext_vector_type(4))) float f32x4;
typedef __attribute__((ext_vector_type(4))) unsigned int u32x4;

__device__ __forceinline__ float b2f(unsigned int u) { return __uint_as_float(u << 16); }
__device__ __forceinline__ unsigned int f2b(float f) {
    unsigned int u = __float_as_uint(f);
    return (u + 0x7fffu + ((u >> 16) & 1u)) >> 16;  // RNE
}
__device__ __forceinline__ void unpack8(uint4 v, float* f) {
    f[0] = b2f(v.x & 0xffffu); f[1] = b2f(v.x >> 16);
    f[2] = b2f(v.y & 0xffffu); f[3] = b2f(v.y >> 16);
    f[4] = b2f(v.z & 0xffffu); f[5] = b2f(v.z >> 16);
    f[6] = b2f(v.w & 0xffffu); f[7] = b2f(v.w >> 16);
}
__device__ __forceinline__ uint4 pack8(const float* f) {
    uint4 v;
    v.x = f2b(f[0]) | (f2b(f[1]) << 16);
    v.y = f2b(f[2]) | (f2b(f[3]) << 16);
    v.z = f2b(f[4]) | (f2b(f[5]) << 16);
    v.w = f2b(f[6]) | (f2b(f[7]) << 16);
    return v;
}
// nontemporal 16B store (keep L2 for h)
__device__ __forceinline__ void nt_store16(uint4 v, ushort* p) {
    u32x4 w = {v.x, v.y, v.z, v.w};
    __builtin_nontemporal_store(w, (u32x4*)p);
}

// async 16B global->LDS (gfx950)
__device__ __forceinline__ void gload_lds16(const void* g, void* l) {
    __builtin_amdgcn_global_load_lds((__attribute__((address_space(1))) void*)g,
                                     (__attribute__((address_space(3))) void*)l, 16, 0, 0);
}

// Inline BN-param build (cross-kernel consumers; plain loads are safe there).
__device__ __forceinline__ void build_bnp(const float* __restrict__ st, const float* __restrict__ gma,
                                          const float* __restrict__ bta, float (*bnp)[DD], int t) {
    if (t < DD) {
        float s = 0.f, q = 0.f;
        #pragma unroll
        for (int r = 0; r < 8; ++r) { s += st[r * DD + t]; q += st[8 * DD + r * DD + t]; }
        const float invn = 1.0f / NN;
        float m = s * invn;
        float var = q * invn - m * m;
        float sc = gma[t] * rsqrtf(var + 1e-5f);
        bnp[0][t] = sc;
        bnp[1][t] = bta[t] - m * sc;
    }
}

// ---------------- fused init ----------------
__global__ __launch_bounds__(256) void k_init(const float* __restrict__ x, ushort* __restrict__ h,
                                              float* __restrict__ pz, int nz, int* __restrict__ deg,
                                              const float* __restrict__ w1, const float* __restrict__ w2,
                                              ushort* __restrict__ wp) {
    const int T = gridDim.x * 256;
    const int tid = blockIdx.x * 256 + threadIdx.x;
    for (int i = tid; i < NN * DD / 8; i += T) {
        float4 a = ((const float4*)x)[2 * i], b = ((const float4*)x)[2 * i + 1];
        float f[8] = {a.x, a.y, a.z, a.w, b.x, b.y, b.z, b.w};
        ((uint4*)h)[i] = pack8(f);
    }
    for (int i = tid; i < nz; i += T) pz[i] = 0.f;
    for (int i = tid; i < NN; i += T) deg[i] = 0;
    for (int id = tid; id < 16384; id += T) {
        int v = id & 63;
        int kc = (id >> 6) & 3;
        int ct = (id >> 8) & 7;
        int m = id >> 11;
        const float* W = (m < 4) ? (w1 + (size_t)m * DD * DD) : (w2 + (size_t)(m - 4) * DD * DD);
        int c = ct * 16 + (v & 15);
        int kbase = kc * 32 + ((v >> 4) << 3);
        ushort* dst = wp + ((size_t)id << 3);
        #pragma unroll
        for (int j = 0; j < 8; ++j) dst[j] = (ushort)f2b(W[(size_t)(kbase + j) * DD + c]);
    }
}

// ---------------- CSR build ----------------

__global__ __launch_bounds__(256) void k_hist(const int* __restrict__ dst, int* __restrict__ deg) {
    int e = blockIdx.x * 256 + threadIdx.x;
    if (e < NE) atomicAdd(&deg[dst[e]], 1);
}
__global__ __launch_bounds__(256) void k_partial(const int* __restrict__ deg, int* __restrict__ part) {
    __shared__ int s[256];
    int t = threadIdx.x;
    int i = blockIdx.x * 256 + t;
    s[t] = (i < NN) ? deg[i] : 0;
    __syncthreads();
    #pragma unroll
    for (int off = 128; off >= 1; off >>= 1) {
        if (t < off) s[t] += s[t + off];
        __syncthreads();
    }
    if (t == 0) part[blockIdx.x] = s[0];
}
__global__ __launch_bounds__(512) void k_scanpart(int* __restrict__ part, int nb) {
    __shared__ int s[512];
    int t = threadIdx.x;
    int v = (t < nb) ? part[t] : 0;
    s[t] = v;
    __syncthreads();
    #pragma unroll
    for (int off = 1; off < 512; off <<= 1) {
        int add = (t >= off) ? s[t - off] : 0;
        __syncthreads();
        s[t] += add;
        __syncthreads();
    }
    if (t < nb) part[t] = s[t] - v;
}
__global__ __launch_bounds__(256) void k_exscan(const int* __restrict__ deg, const int* __restrict__ part,
                                                int* __restrict__ rowofs, int* __restrict__ cursor) {
    __shared__ int s[256];
    int b = blockIdx.x, t = threadIdx.x;
    int i = b * 256 + t;
    int v = (i < NN) ? deg[i] : 0;
    s[t] = v;
    __syncthreads();
    #pragma unroll
    for (int off = 1; off < 256; off <<= 1) {
        int add = (t >= off) ? s[t - off] : 0;
        __syncthreads();
        s[t] += add;
        __syncthreads();
    }
    if (i < NN) {
        int r = part[b] + s[t] - v;
        rowofs[i] = r;
        cursor[i] = r;
    }
    if (i == NN - 1) rowofs[NN] = part[b] + s[t];
}
__global__ __launch_bounds__(256) void k_fill(const int* __restrict__ src, const int* __restrict__ dst,
                                              int* __restrict__ cursor, int* __restrict__ csr) {
    int e = blockIdx.x * 256 + threadIdx.x;
    if (e >= NE) return;
    int d = dst[e];
    int pos = atomicAdd(&cursor[d], 1);
    csr[pos] = src[e];
}

// ---------------- gather + fused per-graph pooling (bf16, inline-BN+ReLU) ----------------
template<bool BN>
__global__ __launch_bounds__(256) void k_gather(const int* __restrict__ rowofs, const int* __restrict__ csr,
                                                const int* __restrict__ batch,
                                                const ushort* __restrict__ h, ushort* __restrict__ z,
                                                const float* __restrict__ st, const float* __restrict__ gma,
                                                const float* __restrict__ bta,
                                                float* __restrict__ poolslot) {
    __shared__ float bnp[2][DD];
    __shared__ float sfl[16][DD];
    __shared__ int gids[16];
    int t = threadIdx.x;
    if (BN) build_bnp(st, gma, bta, bnp, t);
    int rs = t >> 4;
    int n = blockIdx.x * 16 + rs;
    int cl = t & 15;
    int cb = cl * 8;
    if (cl == 0) gids[rs] = batch[n];
    uint4 v = ((const uint4*)h)[(size_t)n * 16 + cl];   // self row in flight
    if (BN) __syncthreads();   // bnp ready
    float sc[8], sh[8];
    if (BN) {
        #pragma unroll
        for (int j = 0; j < 8; ++j) { sc[j] = bnp[0][cb + j]; sh[j] = bnp[1][cb + j]; }
    }
    float acc[8], f[8];
    unpack8(v, f);
    #pragma unroll
    for (int j = 0; j < 8; ++j)
        acc[j] = BN ? fmaxf(fmaf(f[j], sc[j], sh[j]), 0.f) : f[j];
    #pragma unroll
    for (int j = 0; j < 8; j += 4)
        *(float4*)(&sfl[rs][cb + j]) = make_float4(acc[j], acc[j + 1], acc[j + 2], acc[j + 3]);
    __syncthreads();           // sfl + gids ready
    if (t < DD) {
        float run = sfl[0][t];
        int gprev = gids[0];
        #pragma unroll
        for (int s = 1; s < 16; ++s) {
            int gg = gids[s];
            float vv = sfl[s][t];
            if (gg != gprev) {
                atomicAdd(poolslot + (size_t)gprev * DD + t, run);
                run = 0.f;
                gprev = gg;
            }
            run += vv;
        }
        atomicAdd(poolslot + (size_t)gprev * DD + t, run);
    }
    int e = rowofs[n], end = rowofs[n + 1];
    int i0 = 0, i1 = 0, i2 = 0, i3 = 0;
    if (e + 3 < end) { i0 = csr[e]; i1 = csr[e + 1]; i2 = csr[e + 2]; i3 = csr[e + 3]; }
    while (e + 3 < end) {
        uint4 v0 = ((const uint4*)h)[(size_t)i0 * 16 + cl];
        uint4 v1 = ((const uint4*)h)[(size_t)i1 * 16 + cl];
        uint4 v2 = ((const uint4*)h)[(size_t)i2 * 16 + cl];
        uint4 v3 = ((const uint4*)h)[(size_t)i3 * 16 + cl];
        int en = e + 4;
        if (en + 3 < end) {
            i0 = csr[en]; i1 = csr[en + 1]; i2 = csr[en + 2]; i3 = csr[en + 3];
        }
        float f0[8], f1[8], f2[8], f3[8];
        unpack8(v0, f0); unpack8(v1, f1); unpack8(v2, f2); unpack8(v3, f3);
        #pragma unroll
        for (int j = 0; j < 8; ++j) {
            float a0 = BN ? fmaxf(fmaf(f0[j], sc[j], sh[j]), 0.f) : f0[j];
            float a1 = BN ? fmaxf(fmaf(f1[j], sc[j], sh[j]), 0.f) : f1[j];
            float a2 = BN ? fmaxf(fmaf(f2[j], sc[j], sh[j]), 0.f) : f2[j];
            float a3 = BN ? fmaxf(fmaf(f3[j], sc[j], sh[j]), 0.f) : f3[j];
            acc[j] += (a0 + a1) + (a2 + a3);
        }
        e = en;
    }
    for (; e < end; ++e) {
        uint4 v0 = ((const uint4*)h)[(size_t)csr[e] * 16 + cl];
        float f0[8];
        unpack8(v0, f0);
        #pragma unroll
        for (int j = 0; j < 8; ++j)
            acc[j] += BN ? fmaxf(fmaf(f0[j], sc[j], sh[j]), 0.f) : f0[j];
    }
    nt_store16(pack8(acc), z + ((size_t)n * 16 + cl) * 8);
}

// ---------------- fused mm1+mm2 (cooperative): Y1 lives in LDS ----------------
// grid 782 x 128 rows. Phase1: Z@W1+b1 -> LDS (bf16) + stats. grid.sync().
// BN params from device-coherent loads; in-place BN+ReLU on LDS; Phase2:
// LDS@W2+b2 -> H global + stats.
__global__ __launch_bounds__(256, 4) void k_mmfused(
        const ushort* __restrict__ zin, const ushort* __restrict__ wp1, const ushort* __restrict__ wp2,
        const float* __restrict__ b1v, const float* __restrict__ b2v,
        float* __restrict__ stmid, const float* __restrict__ gma, const float* __restrict__ bta,
        ushort* __restrict__ hout, float* __restrict__ stout) {
    __shared__ __align__(16) char lds[32768];   // 2 x 16KB subtile slots (Y1-resident)
    __shared__ float bnp[2][DD];
    __shared__ float red8[8 * DD];
    const int t = threadIdx.x;
    const int lane = t & 63;
    const int wid = t >> 6;
    const int wr = wid >> 1, wc = wid & 1;
    const int rb0 = blockIdx.x * 128;
    const int rep = blockIdx.x & 7;

    float s8[8], q8[8];
    #pragma unroll
    for (int j = 0; j < 8; ++j) { s8[j] = 0.f; q8[j] = 0.f; }

    // ---------------- phase 1 ----------------
    #pragma unroll
    for (int s = 0; s < 2; ++s) {
        const int rb = rb0 + s * 64;
        char* slot = lds + s * 16384;
        if (rb + 64 <= NN) {
            #pragma unroll
            for (int i = 0; i < 4; ++i) {
                int p = i * 256 + t;
                int row = p >> 4;
                int oc = (p & 15) ^ (row & 7);
                gload_lds16((const uint4*)zin + (size_t)(rb + row) * 16 + oc, slot + p * 16);
            }
        } else {
            #pragma unroll
            for (int i = 0; i < 4; ++i) {
                int c = i * 256 + t;
                int row = c >> 4;
                int g = rb + row;
                uint4 v = make_uint4(0, 0, 0, 0);
                if (g < NN) v = *((const uint4*)zin + (size_t)g * 16 + (c & 15));
                *(uint4*)(slot + ((c * 16) ^ ((row & 7) << 4))) = v;
            }
        }
        __syncthreads();

        f32x4 acc[2][4];
        #pragma unroll
        for (int rt = 0; rt < 2; ++rt)
            #pragma unroll
            for (int ct = 0; ct < 4; ++ct) acc[rt][ct] = (f32x4){0.f, 0.f, 0.f, 0.f};
        #pragma unroll
        for (int kc = 0; kc < 4; ++kc) {
            short8 wf[4];
            #pragma unroll
            for (int ct = 0; ct < 4; ++ct)
                wf[ct] = *(const short8*)(wp1 + (size_t)((((wc * 4 + ct) * 4 + kc) * 64 + lane) << 3));
            #pragma unroll
            for (int rt = 0; rt < 2; ++rt) {
                int row = wr * 32 + rt * 16 + (lane & 15);
                int off = (row * 256 + ((kc * 32 + ((lane >> 4) << 3)) << 1)) ^ ((row & 7) << 4);
                short8 zf = *(const short8*)(slot + off);
                #pragma unroll
                for (int ct = 0; ct < 4; ++ct)
                    acc[rt][ct] = __builtin_amdgcn_mfma_f32_16x16x32_bf16(wf[ct], zf, acc[rt][ct], 0, 0, 0);
            }
        }
        __syncthreads();
        const int zr = lane & 15, cq = lane >> 4;
        #pragma unroll
        for (int rt = 0; rt < 2; ++rt) {
            int row = wr * 32 + rt * 16 + zr;
            #pragma unroll
            for (int ct = 0; ct < 4; ++ct) {
                int c0 = wc * 64 + ct * 16 + cq * 4;
                float4 bi = *(const float4*)(b1v + c0);
                f32x4 a = acc[rt][ct];
                uint2 pk;
                pk.x = f2b(a[0] + bi.x) | (f2b(a[1] + bi.y) << 16);
                pk.y = f2b(a[2] + bi.z) | (f2b(a[3] + bi.w) << 16);
                *(uint2*)(slot + ((row * 256 + c0 * 2) ^ ((row & 7) << 4))) = pk;
            }
        }
        __syncthreads();
        // stats read-back (no global store; Y1 stays in LDS)
        #pragma unroll
        for (int i = 0; i < 4; ++i) {
            int c = i * 256 + t;
            int row = c >> 4;
            int g = rb + row;
            if (g < NN) {
                uint4 v = *(const uint4*)(slot + ((c * 16) ^ ((row & 7) << 4)));
                float f[8];
                unpack8(v, f);
                #pragma unroll
                for (int j = 0; j < 8; ++j) { s8[j] += f[j]; q8[j] += f[j] * f[j]; }
            }
        }
    }
    #pragma unroll
    for (int j = 0; j < 8; ++j) {
        s8[j] += __shfl_xor(s8[j], 16); s8[j] += __shfl_xor(s8[j], 32);
        q8[j] += __shfl_xor(q8[j], 16); q8[j] += __shfl_xor(q8[j], 32);
    }
    if (lane < 16) {
        #pragma unroll
        for (int j = 0; j < 8; j += 4) {
            *(float4*)(red8 + wid * DD + lane * 8 + j) = make_float4(s8[j], s8[j+1], s8[j+2], s8[j+3]);
            *(float4*)(red8 + 4 * DD + wid * DD + lane * 8 + j) = make_float4(q8[j], q8[j+1], q8[j+2], q8[j+3]);
        }
    }
    __syncthreads();
    if (t < DD) {
        float s = red8[t] + red8[DD + t] + red8[2 * DD + t] + red8[3 * DD + t];
        float q = red8[4 * DD + t] + red8[5 * DD + t] + red8[6 * DD + t] + red8[7 * DD + t];
        atomicAdd(stmid + rep * DD + t, s);
        atomicAdd(stmid + 8 * DD + rep * DD + t, q);
    }
    __threadfence();
    cg::this_grid().sync();

    // ---------------- BN params + in-place transform ----------------
    if (t < DD) {
        float s = 0.f, q = 0.f;
        #pragma unroll
        for (int r = 0; r < 8; ++r) {
            s += __hip_atomic_load(stmid + r * DD + t, __ATOMIC_RELAXED, __HIP_MEMORY_SCOPE_AGENT);
            q += __hip_atomic_load(stmid + 8 * DD + r * DD + t, __ATOMIC_RELAXED, __HIP_MEMORY_SCOPE_AGENT);
        }
        const float invn = 1.0f / NN;
        float m = s * invn;
        float var = q * invn - m * m;
        float sc = gma[t] * rsqrtf(var + 1e-5f);
        bnp[0][t] = sc;
        bnp[1][t] = bta[t] - m * sc;
    }
    __syncthreads();
    #pragma unroll
    for (int i = 0; i < 8; ++i) {
        int p = i * 256 + t;                       // chunk position across both slots
        int cb = ((p ^ ((p >> 4) & 7)) & 15) * 8;  // column octet stored there
        uint4 v = *(const uint4*)(lds + p * 16);
        float f[8];
        unpack8(v, f);
        #pragma unroll
        for (int j = 0; j < 8; ++j) f[j] = fmaxf(fmaf(f[j], bnp[0][cb + j], bnp[1][cb + j]), 0.f);
        *(uint4*)(lds + p * 16) = pack8(f);
    }
    __syncthreads();

    // ---------------- phase 2 ----------------
    #pragma unroll
    for (int j = 0; j < 8; ++j) { s8[j] = 0.f; q8[j] = 0.f; }
    #pragma unroll
    for (int s = 0; s < 2; ++s) {
        const int rb = rb0 + s * 64;
        char* slot = lds + s * 16384;
        f32x4 acc[2][4];
        #pragma unroll
        for (int rt = 0; rt < 2; ++rt)
            #pragma unroll
            for (int ct = 0; ct < 4; ++ct) acc[rt][ct] = (f32x4){0.f, 0.f, 0.f, 0.f};
        #pragma unroll
        for (int kc = 0; kc < 4; ++kc) {
            short8 wf[4];
            #pragma unroll
            for (int ct = 0; ct < 4; ++ct)
                wf[ct] = *(const short8*)(wp2 + (size_t)((((wc * 4 + ct) * 4 + kc) * 64 + lane) << 3));
            #pragma unroll
            for (int rt = 0; rt < 2; ++rt) {
                int row = wr * 32 + rt * 16 + (lane & 15);
                int off = (row * 256 + ((kc * 32 + ((lane >> 4) << 3)) << 1)) ^ ((row & 7) << 4);
                short8 zf = *(const short8*)(slot + off);
                #pragma unroll
                for (int ct = 0; ct < 4; ++ct)
                    acc[rt][ct] = __builtin_amdgcn_mfma_f32_16x16x32_bf16(wf[ct], zf, acc[rt][ct], 0, 0, 0);
            }
        }
        __syncthreads();
        const int zr = lane & 15, cq = lane >> 4;
        #pragma unroll
        for (int rt = 0; rt < 2; ++rt) {
            int row = wr * 32 + rt * 16 + zr;
            #pragma unroll
            for (int ct = 0; ct < 4; ++ct) {
                int c0 = wc * 64 + ct * 16 + cq * 4;
                float4 bi = *(const float4*)(b2v + c0);
                f32x4 a = acc[rt][ct];
                uint2 pk;
                pk.x = f2b(a[0] + bi.x) | (f2b(a[1] + bi.y) << 16);
                pk.y = f2b(a[2] + bi.z) | (f2b(a[3] + bi.w) << 16);
                *(uint2*)(slot + ((row * 256 + c0 * 2) ^ ((row & 7) << 4))) = pk;
            }
        }
        __syncthreads();
        #pragma unroll
        for (int i = 0; i < 4; ++i) {
            int c = i * 256 + t;
            int row = c >> 4;
            int g = rb + row;
            if (g < NN) {
                uint4 v = *(const uint4*)(slot + ((c * 16) ^ ((row & 7) << 4)));
                ((uint4*)hout)[(size_t)g * 16 + (c & 15)] = v;
                float f[8];
                unpack8(v, f);
                #pragma unroll
                for (int j = 0; j < 8; ++j) { s8[j] += f[j]; q8[j] += f[j] * f[j]; }
            }
        }
        __syncthreads();
    }
    #pragma unroll
    for (int j = 0; j < 8; ++j) {
        s8[j] += __shfl_xor(s8[j], 16); s8[j] += __shfl_xor(s8[j], 32);
        q8[j] += __shfl_xor(q8[j], 16); q8[j] += __shfl_xor(q8[j], 32);
    }
    if (lane < 16) {
        #pragma unroll
        for (int j = 0; j < 8; j += 4) {
            *(float4*)(red8 + wid * DD + lane * 8 + j) = make_float4(s8[j], s8[j+1], s8[j+2], s8[j+3]);
            *(float4*)(red8 + 4 * DD + wid * DD + lane * 8 + j) = make_float4(q8[j], q8[j+1], q8[j+2], q8[j+3]);
        }
    }
    __syncthreads();
    if (t < DD) {
        float s = red8[t] + red8[DD + t] + red8[2 * DD + t] + red8[3 * DD + t];
        float q = red8[4 * DD + t] + red8[5 * DD + t] + red8[6 * DD + t] + red8[7 * DD + t];
        atomicAdd(stout + rep * DD + t, s);
        atomicAdd(stout + 8 * DD + rep * DD + t, q);
    }
}

// ---------------- fallback MFMA GEMM (64-row tile, swapped operands, inline BN) ----------------
template<bool TRANS>
__global__ __launch_bounds__(256, 4) void k_mm(const ushort* __restrict__ in, const ushort* __restrict__ wp,
                                               const float* __restrict__ bias,
                                               const float* __restrict__ stin, const float* __restrict__ gma,
                                               const float* __restrict__ bta,
                                               ushort* __restrict__ outp, float* __restrict__ stout) {
    __shared__ __align__(16) char lds[16384];
    __shared__ float bnp[2][DD];
    const int t = threadIdx.x;
    const int lane = t & 63;
    const int wid = t >> 6;
    const int wr = wid >> 1, wc = wid & 1;
    const int rb = blockIdx.x * 64;
    const int rep = blockIdx.x & 7;

    if (TRANS) {
        build_bnp(stin, gma, bta, bnp, t);
        __syncthreads();
    }
    if (!TRANS && rb + 64 <= NN) {
        #pragma unroll
        for (int i = 0; i < 4; ++i) {
            int p = i * 256 + t;
            int row = p >> 4;
            int oc = (p & 15) ^ (row & 7);
            gload_lds16((const uint4*)in + (size_t)(rb + row) * 16 + oc, lds + p * 16);
        }
    } else {
        float scv[8], shv[8];
        if (TRANS) {
            int cb = (t & 15) * 8;
            #pragma unroll
            for (int j = 0; j < 8; ++j) { scv[j] = bnp[0][cb + j]; shv[j] = bnp[1][cb + j]; }
        }
        #pragma unroll
        for (int i = 0; i < 4; ++i) {
            int c = i * 256 + t;
            int row = c >> 4;
            int g = rb + row;
            uint4 v = make_uint4(0, 0, 0, 0);
            if (g < NN) {
                v = *((const uint4*)in + (size_t)g * 16 + (c & 15));
                if (TRANS) {
                    float f[8];
                    unpack8(v, f);
                    #pragma unroll
                    for (int j = 0; j < 8; ++j) f[j] = fmaxf(fmaf(f[j], scv[j], shv[j]), 0.f);
                    v = pack8(f);
                }
            }
            *(uint4*)(lds + ((c * 16) ^ ((row & 7) << 4))) = v;
        }
    }
    __syncthreads();

    f32x4 acc[2][4];
    #pragma unroll
    for (int rt = 0; rt < 2; ++rt)
        #pragma unroll
        for (int ct = 0; ct < 4; ++ct) acc[rt][ct] = (f32x4){0.f, 0.f, 0.f, 0.f};

    #pragma unroll
    for (int kc = 0; kc < 4; ++kc) {
        short8 wf[4];
        #pragma unroll
        for (int ct = 0; ct < 4; ++ct)
            wf[ct] = *(const short8*)(wp + (size_t)((((wc * 4 + ct) * 4 + kc) * 64 + lane) << 3));
        #pragma unroll
        for (int rt = 0; rt < 2; ++rt) {
            int row = wr * 32 + rt * 16 + (lane & 15);
            int off = (row * 256 + ((kc * 32 + ((lane >> 4) << 3)) << 1)) ^ ((row & 7) << 4);
            short8 zf = *(const short8*)(lds + off);
            #pragma unroll
            for (int ct = 0; ct < 4; ++ct)
                acc[rt][ct] = __builtin_amdgcn_mfma_f32_16x16x32_bf16(wf[ct], zf, acc[rt][ct], 0, 0, 0);
        }
    }
    __syncthreads();

    const int zr = lane & 15, cq = lane >> 4;
    #pragma unroll
    for (int rt = 0; rt < 2; ++rt) {
        int row = wr * 32 + rt * 16 + zr;
        #pragma unroll
        for (int ct = 0; ct < 4; ++ct) {
            int c0 = wc * 64 + ct * 16 + cq * 4;
            float4 bi = *(const float4*)(bias + c0);
            f32x4 a = acc[rt][ct];
            uint2 pk;
            pk.x = f2b(a[0] + bi.x) | (f2b(a[1] + bi.y) << 16);
            pk.y = f2b(a[2] + bi.z) | (f2b(a[3] + bi.w) << 16);
            *(uint2*)(lds + ((row * 256 + c0 * 2) ^ ((row & 7) << 4))) = pk;
        }
    }
    __syncthreads();

    float s8[8], q8[8];
    #pragma unroll
    for (int j = 0; j < 8; ++j) { s8[j] = 0.f; q8[j] = 0.f; }
    #pragma unroll
    for (int i = 0; i < 4; ++i) {
        int c = i * 256 + t;
        int row = c >> 4;
        int g = rb + row;
        if (g < NN) {
            uint4 v = *(const uint4*)(lds + ((c * 16) ^ ((row & 7) << 4)));
            ((uint4*)outp)[(size_t)g * 16 + (c & 15)] = v;
            float f[8];
            unpack8(v, f);
            #pragma unroll
            for (int j = 0; j < 8; ++j) { s8[j] += f[j]; q8[j] += f[j] * f[j]; }
        }
    }
    #pragma unroll
    for (int j = 0; j < 8; ++j) {
        s8[j] += __shfl_xor(s8[j], 16); s8[j] += __shfl_xor(s8[j], 32);
        q8[j] += __shfl_xor(q8[j], 16); q8[j] += __shfl_xor(q8[j], 32);
    }
    __syncthreads();
    float* rs2 = (float*)lds;
    if (lane < 16) {
        #pragma unroll
        for (int j = 0; j < 8; j += 4) {
            *(float4*)(rs2 + wid * DD + lane * 8 + j) = make_float4(s8[j], s8[j+1], s8[j+2], s8[j+3]);
            *(float4*)(rs2 + 4 * DD + wid * DD + lane * 8 + j) = make_float4(q8[j], q8[j+1], q8[j+2], q8[j+3]);
        }
    }
    __syncthreads();
    if (t < DD) {
        float s = rs2[t] + rs2[DD + t] + rs2[2 * DD + t] + rs2[3 * DD + t];
        float q = rs2[4 * DD + t] + rs2[5 * DD + t] + rs2[6 * DD + t] + rs2[7 * DD + t];
        atomicAdd(stout + rep * DD + t, s);
        atomicAdd(stout + 8 * DD + rep * DD + t, q);
    }
}

// ---------------- fused final pooling + readout ----------------
__device__ __forceinline__ int lowerb(const int* __restrict__ a, int n, int key) {
    int lo = 0, hi = n;
    while (lo < hi) {
        int mid = (lo + hi) >> 1;
        if (a[mid] < key) lo = mid + 1; else hi = mid;
    }
    return lo;
}

__global__ __launch_bounds__(256) void k_poolread(const int* __restrict__ batch, const ushort* __restrict__ h,
                                                  const float* __restrict__ pooled,
                                                  const float* __restrict__ st, const float* __restrict__ gma,
                                                  const float* __restrict__ bta,
                                                  const float* __restrict__ fcw, const float* __restrict__ fcb,
                                                  float* __restrict__ out) {
    __shared__ float bnp[2][DD];
    __shared__ float red[16 * DD];
    __shared__ float ps[2][NC];
    int t = threadIdx.x;
    build_bnp(st, gma, bta, bnp, t);
    __syncthreads();
    int g = blockIdx.x;
    int cl = t & 15;
    int rs = t >> 4;
    int cb = cl * 8;
    float sc[8], sh[8];
    #pragma unroll
    for (int j = 0; j < 8; ++j) { sc[j] = bnp[0][cb + j]; sh[j] = bnp[1][cb + j]; }
    int start = lowerb(batch, NN, g);
    int end = lowerb(batch, NN, g + 1);
    float acc[8];
    #pragma unroll
    for (int j = 0; j < 8; ++j) acc[j] = 0.f;
    for (int n = start + rs; n < end; n += 16) {
        uint4 v = ((const uint4*)h)[(size_t)n * 16 + cl];
        float f[8];
        unpack8(v, f);
        #pragma unroll
        for (int j = 0; j < 8; ++j)
            acc[j] += fmaxf(fmaf(f[j], sc[j], sh[j]), 0.f);
    }
    #pragma unroll
    for (int j = 0; j < 8; j += 4)
        *(float4*)(red + rs * DD + cb + j) = make_float4(acc[j], acc[j + 1], acc[j + 2], acc[j + 3]);
    __syncthreads();
    #pragma unroll
    for (int off = 8; off >= 1; off >>= 1) {
        if (rs < off) {
            #pragma unroll
            for (int j = 0; j < 8; j += 4) {
                float4 a = *(float4*)(red + rs * DD + cb + j);
                float4 b = *(float4*)(red + (rs + off) * DD + cb + j);
                a.x += b.x; a.y += b.y; a.z += b.z; a.w += b.w;
                *(float4*)(red + rs * DD + cb + j) = a;
            }
        }
        __syncthreads();
    }
    if (t < DD) {
        int d = t;
        float part[NC];
        #pragma unroll
        for (int c = 0; c < NC; ++c) part[c] = 0.f;
        #pragma unroll
        for (int i = 0; i < NL; ++i) {
            float v = pooled[((size_t)i * NG + g) * DD + d];
            const float* wr = fcw + ((size_t)i * DD + d) * NC;
            #pragma unroll
            for (int c = 0; c < NC; ++c) part[c] = fmaf(v, wr[c], part[c]);
        }
        {
            float v = red[d];
            const float* wr = fcw + ((size_t)NL * DD + d) * NC;
            #pragma unroll
            for (int c = 0; c < NC; ++c) part[c] = fmaf(v, wr[c], part[c]);
        }
        #pragma unroll
        for (int off = 32; off >= 1; off >>= 1) {
            #pragma unroll
            for (int c = 0; c < NC; ++c) part[c] += __shfl_down(part[c], off);
        }
        if ((t & 63) == 0) {
            #pragma unroll
            for (int c = 0; c < NC; ++c) ps[t >> 6][c] = part[c];
        }
    }
    __syncthreads();
    if (t == 0) {
        float y[NC];
        #pragma unroll
        for (int c = 0; c < NC; ++c) {
            float bs = 0.f;
            for (int i = 0; i < NL + 1; ++i) bs += fcb[i * NC + c];
            y[c] = ps[0][c] + ps[1][c] + bs;
        }
        float m = y[0];
        #pragma unroll
        for (int c = 1; c < NC; ++c) m = fmaxf(m, y[c]);
        float sum = 0.f;
        #pragma unroll
        for (int c = 0; c < NC; ++c) sum += expf(y[c] - m);
        float ls = logf(sum);
        #pragma unroll
        for (int c = 0; c < NC; ++c) out[(size_t)g * NC + c] = y[c] - m - ls;
    }
}

// ---------------- launch ----------------

extern "C" void kernel_launch(void* const* d_in, const int* in_sizes, int n_in,
                              void* d_out, int out_size, void* d_ws, size_t ws_size,
                              hipStream_t stream) {
    const float* x   = (const float*)d_in[0];
    const int*   ei  = (const int*)d_in[1];
    const int*   bat = (const int*)d_in[2];
    const float* w1  = (const float*)d_in[3];
    const float* b1  = (const float*)d_in[4];
    const float* mbg = (const float*)d_in[5];
    const float* mbb = (const float*)d_in[6];
    const float* w2  = (const float*)d_in[7];
    const float* b2  = (const float*)d_in[8];
    const float* bng = (const float*)d_in[9];
    const float* bnb = (const float*)d_in[10];
    const float* fcw = (const float*)d_in[11];
    const float* fcb = (const float*)d_in[12];
    float* out = (float*)d_out;

    ushort* H  = (ushort*)d_ws;
    ushort* Z  = H + (size_t)NN * DD;
    ushort* Y1 = Z + (size_t)NN * DD;                 // used only by fallback path
    ushort* WP = Y1 + (size_t)NN * DD;
    float* pooled = (float*)(WP + 8 * 16384);
    float* stats  = pooled + (size_t)NL * NG * DD;
    int* deg    = (int*)(stats + 8 * 16 * DD);
    int* rowofs = deg + NN;
    int* part   = rowofs + NN + 1;
    int* cursor = part + 512;
    int* csr    = cursor + NN;

    const int* src = ei;
    const int* dst = ei + NE;
    const int nbN = (NN + 255) / 256;
    const int nbE = (NE + 255) / 256;
    const int nzero = NL * NG * DD + 8 * 16 * DD;

    hipLaunchKernelGGL(k_init, dim3(NN * DD / 8 / 256 + 1), dim3(256), 0, stream,
                       x, H, pooled, nzero, deg, w1, w2, WP);
    hipLaunchKernelGGL(k_hist, dim3(nbE), dim3(256), 0, stream, dst, deg);
    hipLaunchKernelGGL(k_partial, dim3(nbN), dim3(256), 0, stream, deg, part);
    hipLaunchKernelGGL(k_scanpart, dim3(1), dim3(512), 0, stream, part, nbN);
    hipLaunchKernelGGL(k_exscan, dim3(nbN), dim3(256), 0, stream, deg, part, rowofs, cursor);
    hipLaunchKernelGGL(k_fill, dim3(nbE), dim3(256), 0, stream, src, dst, cursor, csr);

    const int gmm = (NN + 63) / 64;    // 1563 (fallback)
    const int gfu = (NN + 127) / 128;  // 782 (cooperative fused)
    const int ggt = NN / 16;           // 6250
    const int SLOT = 16 * DD;
    for (int i = 0; i < NL; ++i) {
        float* st_mlp = stats + (size_t)(2 * i + 0) * SLOT;
        float* st_out = stats + (size_t)(2 * i + 1) * SLOT;
        const float* st_prev = stats + (size_t)(2 * i - 1) * SLOT;
        float* poolslot = pooled + (size_t)i * NG * DD;
        if (i == 0) {
            hipLaunchKernelGGL((k_gather<false>), dim3(ggt), dim3(256), 0, stream, rowofs, csr, bat, H, Z,
                               (const float*)nullptr, (const float*)nullptr, (const float*)nullptr, poolslot);
        } else {
            hipLaunchKernelGGL((k_gather<true>), dim3(ggt), dim3(256), 0, stream, rowofs, csr, bat, H, Z,
                               st_prev, bng + (size_t)(i - 1) * DD, bnb + (size_t)(i - 1) * DD, poolslot);
        }
        // cooperative fused mm1+mm2; fallback to two-kernel path on failure
        {
            const ushort* zf = Z;
            const ushort* wp1 = WP + (size_t)i * 16384;
            const ushort* wp2 = WP + (size_t)(4 + i) * 16384;
            const float* b1p = b1 + (size_t)i * DD;
            const float* b2p = b2 + (size_t)i * DD;
            float* stmid = st_mlp;
            const float* gmap = mbg + (size_t)i * DD;
            const float* btap = mbb + (size_t)i * DD;
            ushort* hp = H;
            float* stoutp = st_out;
            void* args[] = {&zf, &wp1, &wp2, &b1p, &b2p, &stmid, &gmap, &btap, &hp, &stoutp};
            hipError_t rc = hipLaunchCooperativeKernel((const void*)k_mmfused, dim3(gfu), dim3(256),
                                                       args, 0, stream);
            if (rc != hipSuccess) {
                hipLaunchKernelGGL((k_mm<false>), dim3(gmm), dim3(256), 0, stream,
                                   Z, wp1, b1p,
                                   (const float*)nullptr, (const float*)nullptr, (const float*)nullptr,
                                   Y1, st_mlp);
                hipLaunchKernelGGL((k_mm<true>), dim3(gmm), dim3(256), 0, stream,
                                   Y1, wp2, b2p, st_mlp, gmap, btap, H, st_out);
            }
        }
    }
    hipLaunchKernelGGL(k_poolread, dim3(NG), dim3(256), 0, stream, bat, H, pooled,
                       stats + (size_t)7 * SLOT, bng + (size_t)3 * DD, bnb + (size_t)3 * DD,
                       fcw, fcb, out);
}

// Round 14
// 362.826 us; speedup vs baseline: 2.8196x; 2.8196x over previous
//
#include <hip/hip_runtime.h>

#define NN 100000
#define NE 600000
#define DD 128
#define NG 512
#define NC 10
#define NL 4

typedef __attribute__((ext_vector_type(8))) short short8;
typedef __attribute__((ext_vector_type(4))) float f32x4;
typedef __attribute__((ext_vector_type(4))) unsigned int u32x4;

__device__ __forceinline__ float b2f(unsigned int u) { return __uint_as_float(u << 16); }
__device__ __forceinline__ unsigned int f2b(float f) {
    unsigned int u = __float_as_uint(f);
    return (u + 0x7fffu + ((u >> 16) & 1u)) >> 16;  // RNE
}
__device__ __forceinline__ void unpack8(uint4 v, float* f) {
    f[0] = b2f(v.x & 0xffffu); f[1] = b2f(v.x >> 16);
    f[2] = b2f(v.y & 0xffffu); f[3] = b2f(v.y >> 16);
    f[4] = b2f(v.z & 0xffffu); f[5] = b2f(v.z >> 16);
    f[6] = b2f(v.w & 0xffffu); f[7] = b2f(v.w >> 16);
}
__device__ __forceinline__ uint4 pack8(const float* f) {
    uint4 v;
    v.x = f2b(f[0]) | (f2b(f[1]) << 16);
    v.y = f2b(f[2]) | (f2b(f[3]) << 16);
    v.z = f2b(f[4]) | (f2b(f[5]) << 16);
    v.w = f2b(f[6]) | (f2b(f[7]) << 16);
    return v;
}
// nontemporal 16B store (keep L2 for h)
__device__ __forceinline__ void nt_store16(uint4 v, ushort* p) {
    u32x4 w = {v.x, v.y, v.z, v.w};
    __builtin_nontemporal_store(w, (u32x4*)p);
}

// async 16B global->LDS (gfx950)
__device__ __forceinline__ void gload_lds16(const void* g, void* l) {
    __builtin_amdgcn_global_load_lds((__attribute__((address_space(1))) void*)g,
                                     (__attribute__((address_space(3))) void*)l, 16, 0, 0);
}

// Inline BN-param build: stats slot -> bnp[0][c]=scale, bnp[1][c]=shift.
__device__ __forceinline__ void build_bnp(const float* __restrict__ st, const float* __restrict__ gma,
                                          const float* __restrict__ bta, float (*bnp)[DD], int t) {
    if (t < DD) {
        float s = 0.f, q = 0.f;
        #pragma unroll
        for (int r = 0; r < 8; ++r) { s += st[r * DD + t]; q += st[8 * DD + r * DD + t]; }
        const float invn = 1.0f / NN;
        float m = s * invn;
        float var = q * invn - m * m;
        float sc = gma[t] * rsqrtf(var + 1e-5f);
        bnp[0][t] = sc;
        bnp[1][t] = bta[t] - m * sc;
    }
}

// ---------------- fused init ----------------
__global__ __launch_bounds__(256) void k_init(const float* __restrict__ x, ushort* __restrict__ h,
                                              float* __restrict__ pz, int nz, int* __restrict__ deg,
                                              const float* __restrict__ w1, const float* __restrict__ w2,
                                              ushort* __restrict__ wp) {
    const int T = gridDim.x * 256;
    const int tid = blockIdx.x * 256 + threadIdx.x;
    for (int i = tid; i < NN * DD / 8; i += T) {
        float4 a = ((const float4*)x)[2 * i], b = ((const float4*)x)[2 * i + 1];
        float f[8] = {a.x, a.y, a.z, a.w, b.x, b.y, b.z, b.w};
        ((uint4*)h)[i] = pack8(f);
    }
    for (int i = tid; i < nz; i += T) pz[i] = 0.f;
    for (int i = tid; i < NN; i += T) deg[i] = 0;
    for (int id = tid; id < 16384; id += T) {
        int v = id & 63;
        int kc = (id >> 6) & 3;
        int ct = (id >> 8) & 7;
        int m = id >> 11;
        const float* W = (m < 4) ? (w1 + (size_t)m * DD * DD) : (w2 + (size_t)(m - 4) * DD * DD);
        int c = ct * 16 + (v & 15);
        int kbase = kc * 32 + ((v >> 4) << 3);
        ushort* dst = wp + ((size_t)id << 3);
        #pragma unroll
        for (int j = 0; j < 8; ++j) dst[j] = (ushort)f2b(W[(size_t)(kbase + j) * DD + c]);
    }
}

// ---------------- CSR build ----------------

__global__ __launch_bounds__(256) void k_hist(const int* __restrict__ dst, int* __restrict__ deg) {
    int e = blockIdx.x * 256 + threadIdx.x;
    if (e < NE) atomicAdd(&deg[dst[e]], 1);
}
__global__ __launch_bounds__(256) void k_partial(const int* __restrict__ deg, int* __restrict__ part) {
    __shared__ int s[256];
    int t = threadIdx.x;
    int i = blockIdx.x * 256 + t;
    s[t] = (i < NN) ? deg[i] : 0;
    __syncthreads();
    #pragma unroll
    for (int off = 128; off >= 1; off >>= 1) {
        if (t < off) s[t] += s[t + off];
        __syncthreads();
    }
    if (t == 0) part[blockIdx.x] = s[0];
}
__global__ __launch_bounds__(512) void k_scanpart(int* __restrict__ part, int nb) {
    __shared__ int s[512];
    int t = threadIdx.x;
    int v = (t < nb) ? part[t] : 0;
    s[t] = v;
    __syncthreads();
    #pragma unroll
    for (int off = 1; off < 512; off <<= 1) {
        int add = (t >= off) ? s[t - off] : 0;
        __syncthreads();
        s[t] += add;
        __syncthreads();
    }
    if (t < nb) part[t] = s[t] - v;
}
__global__ __launch_bounds__(256) void k_exscan(const int* __restrict__ deg, const int* __restrict__ part,
                                                int* __restrict__ rowofs, int* __restrict__ cursor) {
    __shared__ int s[256];
    int b = blockIdx.x, t = threadIdx.x;
    int i = b * 256 + t;
    int v = (i < NN) ? deg[i] : 0;
    s[t] = v;
    __syncthreads();
    #pragma unroll
    for (int off = 1; off < 256; off <<= 1) {
        int add = (t >= off) ? s[t - off] : 0;
        __syncthreads();
        s[t] += add;
        __syncthreads();
    }
    if (i < NN) {
        int r = part[b] + s[t] - v;
        rowofs[i] = r;
        cursor[i] = r;
    }
    if (i == NN - 1) rowofs[NN] = part[b] + s[t];
}
__global__ __launch_bounds__(256) void k_fill(const int* __restrict__ src, const int* __restrict__ dst,
                                              int* __restrict__ cursor, int* __restrict__ csr) {
    int e = blockIdx.x * 256 + threadIdx.x;
    if (e >= NE) return;
    int d = dst[e];
    int pos = atomicAdd(&cursor[d], 1);
    csr[pos] = src[e];
}

// ---------------- gather + fused per-graph pooling (bf16, inline-BN+ReLU) ----------------
template<bool BN>
__global__ __launch_bounds__(256) void k_gather(const int* __restrict__ rowofs, const int* __restrict__ csr,
                                                const int* __restrict__ batch,
                                                const ushort* __restrict__ h, ushort* __restrict__ z,
                                                const float* __restrict__ st, const float* __restrict__ gma,
                                                const float* __restrict__ bta,
                                                float* __restrict__ poolslot) {
    __shared__ float bnp[2][DD];
    __shared__ float sfl[16][DD];
    __shared__ int gids[16];
    int t = threadIdx.x;
    if (BN) build_bnp(st, gma, bta, bnp, t);
    int rs = t >> 4;
    int n = blockIdx.x * 16 + rs;
    int cl = t & 15;
    int cb = cl * 8;
    if (cl == 0) gids[rs] = batch[n];
    uint4 v = ((const uint4*)h)[(size_t)n * 16 + cl];   // self row in flight
    if (BN) __syncthreads();   // bnp ready
    float sc[8], sh[8];
    if (BN) {
        #pragma unroll
        for (int j = 0; j < 8; ++j) { sc[j] = bnp[0][cb + j]; sh[j] = bnp[1][cb + j]; }
    }
    float acc[8], f[8];
    unpack8(v, f);
    #pragma unroll
    for (int j = 0; j < 8; ++j)
        acc[j] = BN ? fmaxf(fmaf(f[j], sc[j], sh[j]), 0.f) : f[j];
    #pragma unroll
    for (int j = 0; j < 8; j += 4)
        *(float4*)(&sfl[rs][cb + j]) = make_float4(acc[j], acc[j + 1], acc[j + 2], acc[j + 3]);
    __syncthreads();           // sfl + gids ready
    // pool reduce (run-length over sorted batch ids) by 128 threads
    if (t < DD) {
        float run = sfl[0][t];
        int gprev = gids[0];
        #pragma unroll
        for (int s = 1; s < 16; ++s) {
            int gg = gids[s];
            float vv = sfl[s][t];
            if (gg != gprev) {
                atomicAdd(poolslot + (size_t)gprev * DD + t, run);
                run = 0.f;
                gprev = gg;
            }
            run += vv;
        }
        atomicAdd(poolslot + (size_t)gprev * DD + t, run);
    }
    // neighbor accumulation: 4 independent row loads in flight
    int e = rowofs[n], end = rowofs[n + 1];
    for (; e + 3 < end; e += 4) {
        int s0 = csr[e], s1 = csr[e + 1], s2 = csr[e + 2], s3 = csr[e + 3];
        uint4 v0 = ((const uint4*)h)[(size_t)s0 * 16 + cl];
        uint4 v1 = ((const uint4*)h)[(size_t)s1 * 16 + cl];
        uint4 v2 = ((const uint4*)h)[(size_t)s2 * 16 + cl];
        uint4 v3 = ((const uint4*)h)[(size_t)s3 * 16 + cl];
        float f0[8], f1[8], f2[8], f3[8];
        unpack8(v0, f0); unpack8(v1, f1); unpack8(v2, f2); unpack8(v3, f3);
        #pragma unroll
        for (int j = 0; j < 8; ++j) {
            float a0 = BN ? fmaxf(fmaf(f0[j], sc[j], sh[j]), 0.f) : f0[j];
            float a1 = BN ? fmaxf(fmaf(f1[j], sc[j], sh[j]), 0.f) : f1[j];
            float a2 = BN ? fmaxf(fmaf(f2[j], sc[j], sh[j]), 0.f) : f2[j];
            float a3 = BN ? fmaxf(fmaf(f3[j], sc[j], sh[j]), 0.f) : f3[j];
            acc[j] += (a0 + a1) + (a2 + a3);
        }
    }
    for (; e < end; ++e) {
        uint4 v0 = ((const uint4*)h)[(size_t)csr[e] * 16 + cl];
        float f0[8];
        unpack8(v0, f0);
        #pragma unroll
        for (int j = 0; j < 8; ++j)
            acc[j] += BN ? fmaxf(fmaf(f0[j], sc[j], sh[j]), 0.f) : f0[j];
    }
    nt_store16(pack8(acc), z + ((size_t)n * 16 + cl) * 8);
}

// ---------------- MFMA GEMM (64-row tile, swapped operands, inline BN) ----------------
template<bool TRANS>
__global__ __launch_bounds__(256, 4) void k_mm(const ushort* __restrict__ in, const ushort* __restrict__ wp,
                                               const float* __restrict__ bias,
                                               const float* __restrict__ stin, const float* __restrict__ gma,
                                               const float* __restrict__ bta,
                                               ushort* __restrict__ outp, float* __restrict__ stout) {
    __shared__ __align__(16) char lds[16384];
    __shared__ float bnp[2][DD];
    const int t = threadIdx.x;
    const int lane = t & 63;
    const int wid = t >> 6;
    const int wr = wid >> 1, wc = wid & 1;
    const int rb = blockIdx.x * 64;
    const int rep = blockIdx.x & 7;

    if (TRANS) {
        build_bnp(stin, gma, bta, bnp, t);
        __syncthreads();
    }
    if (!TRANS && rb + 64 <= NN) {
        #pragma unroll
        for (int i = 0; i < 4; ++i) {
            int p = i * 256 + t;
            int row = p >> 4;
            int oc = (p & 15) ^ (row & 7);
            gload_lds16((const uint4*)in + (size_t)(rb + row) * 16 + oc, lds + p * 16);
        }
    } else {
        float scv[8], shv[8];
        if (TRANS) {
            int cb = (t & 15) * 8;
            #pragma unroll
            for (int j = 0; j < 8; ++j) { scv[j] = bnp[0][cb + j]; shv[j] = bnp[1][cb + j]; }
        }
        #pragma unroll
        for (int i = 0; i < 4; ++i) {
            int c = i * 256 + t;
            int row = c >> 4;
            int g = rb + row;
            uint4 v = make_uint4(0, 0, 0, 0);
            if (g < NN) {
                v = *((const uint4*)in + (size_t)g * 16 + (c & 15));
                if (TRANS) {
                    float f[8];
                    unpack8(v, f);
                    #pragma unroll
                    for (int j = 0; j < 8; ++j) f[j] = fmaxf(fmaf(f[j], scv[j], shv[j]), 0.f);
                    v = pack8(f);
                }
            }
            *(uint4*)(lds + ((c * 16) ^ ((row & 7) << 4))) = v;
        }
    }
    __syncthreads();

    f32x4 acc[2][4];
    #pragma unroll
    for (int rt = 0; rt < 2; ++rt)
        #pragma unroll
        for (int ct = 0; ct < 4; ++ct) acc[rt][ct] = (f32x4){0.f, 0.f, 0.f, 0.f};

    #pragma unroll
    for (int kc = 0; kc < 4; ++kc) {
        short8 wf[4];
        #pragma unroll
        for (int ct = 0; ct < 4; ++ct)
            wf[ct] = *(const short8*)(wp + (size_t)((((wc * 4 + ct) * 4 + kc) * 64 + lane) << 3));
        #pragma unroll
        for (int rt = 0; rt < 2; ++rt) {
            int row = wr * 32 + rt * 16 + (lane & 15);
            int off = (row * 256 + ((kc * 32 + ((lane >> 4) << 3)) << 1)) ^ ((row & 7) << 4);
            short8 zf = *(const short8*)(lds + off);
            #pragma unroll
            for (int ct = 0; ct < 4; ++ct)
                acc[rt][ct] = __builtin_amdgcn_mfma_f32_16x16x32_bf16(wf[ct], zf, acc[rt][ct], 0, 0, 0);
        }
    }
    __syncthreads();

    const int zr = lane & 15, cq = lane >> 4;
    #pragma unroll
    for (int rt = 0; rt < 2; ++rt) {
        int row = wr * 32 + rt * 16 + zr;
        #pragma unroll
        for (int ct = 0; ct < 4; ++ct) {
            int c0 = wc * 64 + ct * 16 + cq * 4;
            float4 bi = *(const float4*)(bias + c0);
            f32x4 a = acc[rt][ct];
            uint2 pk;
            pk.x = f2b(a[0] + bi.x) | (f2b(a[1] + bi.y) << 16);
            pk.y = f2b(a[2] + bi.z) | (f2b(a[3] + bi.w) << 16);
            *(uint2*)(lds + ((row * 256 + c0 * 2) ^ ((row & 7) << 4))) = pk;
        }
    }
    __syncthreads();

    float s8[8], q8[8];
    #pragma unroll
    for (int j = 0; j < 8; ++j) { s8[j] = 0.f; q8[j] = 0.f; }
    #pragma unroll
    for (int i = 0; i < 4; ++i) {
        int c = i * 256 + t;
        int row = c >> 4;
        int g = rb + row;
        if (g < NN) {
            uint4 v = *(const uint4*)(lds + ((c * 16) ^ ((row & 7) << 4)));
            ((uint4*)outp)[(size_t)g * 16 + (c & 15)] = v;
            float f[8];
            unpack8(v, f);
            #pragma unroll
            for (int j = 0; j < 8; ++j) { s8[j] += f[j]; q8[j] += f[j] * f[j]; }
        }
    }
    #pragma unroll
    for (int j = 0; j < 8; ++j) {
        s8[j] += __shfl_xor(s8[j], 16); s8[j] += __shfl_xor(s8[j], 32);
        q8[j] += __shfl_xor(q8[j], 16); q8[j] += __shfl_xor(q8[j], 32);
    }
    __syncthreads();
    float* rs2 = (float*)lds;
    if (lane < 16) {
        #pragma unroll
        for (int j = 0; j < 8; j += 4) {
            *(float4*)(rs2 + wid * DD + lane * 8 + j) = make_float4(s8[j], s8[j+1], s8[j+2], s8[j+3]);
            *(float4*)(rs2 + 4 * DD + wid * DD + lane * 8 + j) = make_float4(q8[j], q8[j+1], q8[j+2], q8[j+3]);
        }
    }
    __syncthreads();
    if (t < DD) {
        float s = rs2[t] + rs2[DD + t] + rs2[2 * DD + t] + rs2[3 * DD + t];
        float q = rs2[4 * DD + t] + rs2[5 * DD + t] + rs2[6 * DD + t] + rs2[7 * DD + t];
        atomicAdd(stout + rep * DD + t, s);
        atomicAdd(stout + 8 * DD + rep * DD + t, q);
    }
}

// ---------------- fused final pooling + readout ----------------
__device__ __forceinline__ int lowerb(const int* __restrict__ a, int n, int key) {
    int lo = 0, hi = n;
    while (lo < hi) {
        int mid = (lo + hi) >> 1;
        if (a[mid] < key) lo = mid + 1; else hi = mid;
    }
    return lo;
}

__global__ __launch_bounds__(256) void k_poolread(const int* __restrict__ batch, const ushort* __restrict__ h,
                                                  const float* __restrict__ pooled,
                                                  const float* __restrict__ st, const float* __restrict__ gma,
                                                  const float* __restrict__ bta,
                                                  const float* __restrict__ fcw, const float* __restrict__ fcb,
                                                  float* __restrict__ out) {
    __shared__ float bnp[2][DD];
    __shared__ float red[16 * DD];
    __shared__ float ps[2][NC];
    int t = threadIdx.x;
    build_bnp(st, gma, bta, bnp, t);
    __syncthreads();
    int g = blockIdx.x;
    int cl = t & 15;
    int rs = t >> 4;
    int cb = cl * 8;
    float sc[8], sh[8];
    #pragma unroll
    for (int j = 0; j < 8; ++j) { sc[j] = bnp[0][cb + j]; sh[j] = bnp[1][cb + j]; }
    int start = lowerb(batch, NN, g);
    int end = lowerb(batch, NN, g + 1);
    float acc[8];
    #pragma unroll
    for (int j = 0; j < 8; ++j) acc[j] = 0.f;
    for (int n = start + rs; n < end; n += 16) {
        uint4 v = ((const uint4*)h)[(size_t)n * 16 + cl];
        float f[8];
        unpack8(v, f);
        #pragma unroll
        for (int j = 0; j < 8; ++j)
            acc[j] += fmaxf(fmaf(f[j], sc[j], sh[j]), 0.f);
    }
    #pragma unroll
    for (int j = 0; j < 8; j += 4)
        *(float4*)(red + rs * DD + cb + j) = make_float4(acc[j], acc[j + 1], acc[j + 2], acc[j + 3]);
    __syncthreads();
    #pragma unroll
    for (int off = 8; off >= 1; off >>= 1) {
        if (rs < off) {
            #pragma unroll
            for (int j = 0; j < 8; j += 4) {
                float4 a = *(float4*)(red + rs * DD + cb + j);
                float4 b = *(float4*)(red + (rs + off) * DD + cb + j);
                a.x += b.x; a.y += b.y; a.z += b.z; a.w += b.w;
                *(float4*)(red + rs * DD + cb + j) = a;
            }
        }
        __syncthreads();
    }
    if (t < DD) {
        int d = t;
        float part[NC];
        #pragma unroll
        for (int c = 0; c < NC; ++c) part[c] = 0.f;
        #pragma unroll
        for (int i = 0; i < NL; ++i) {
            float v = pooled[((size_t)i * NG + g) * DD + d];
            const float* wr = fcw + ((size_t)i * DD + d) * NC;
            #pragma unroll
            for (int c = 0; c < NC; ++c) part[c] = fmaf(v, wr[c], part[c]);
        }
        {
            float v = red[d];
            const float* wr = fcw + ((size_t)NL * DD + d) * NC;
            #pragma unroll
            for (int c = 0; c < NC; ++c) part[c] = fmaf(v, wr[c], part[c]);
        }
        #pragma unroll
        for (int off = 32; off >= 1; off >>= 1) {
            #pragma unroll
            for (int c = 0; c < NC; ++c) part[c] += __shfl_down(part[c], off);
        }
        if ((t & 63) == 0) {
            #pragma unroll
            for (int c = 0; c < NC; ++c) ps[t >> 6][c] = part[c];
        }
    }
    __syncthreads();
    if (t == 0) {
        float y[NC];
        #pragma unroll
        for (int c = 0; c < NC; ++c) {
            float bs = 0.f;
            for (int i = 0; i < NL + 1; ++i) bs += fcb[i * NC + c];
            y[c] = ps[0][c] + ps[1][c] + bs;
        }
        float m = y[0];
        #pragma unroll
        for (int c = 1; c < NC; ++c) m = fmaxf(m, y[c]);
        float sum = 0.f;
        #pragma unroll
        for (int c = 0; c < NC; ++c) sum += expf(y[c] - m);
        float ls = logf(sum);
        #pragma unroll
        for (int c = 0; c < NC; ++c) out[(size_t)g * NC + c] = y[c] - m - ls;
    }
}

// ---------------- launch ----------------

extern "C" void kernel_launch(void* const* d_in, const int* in_sizes, int n_in,
                              void* d_out, int out_size, void* d_ws, size_t ws_size,
                              hipStream_t stream) {
    const float* x   = (const float*)d_in[0];
    const int*   ei  = (const int*)d_in[1];
    const int*   bat = (const int*)d_in[2];
    const float* w1  = (const float*)d_in[3];
    const float* b1  = (const float*)d_in[4];
    const float* mbg = (const float*)d_in[5];
    const float* mbb = (const float*)d_in[6];
    const float* w2  = (const float*)d_in[7];
    const float* b2  = (const float*)d_in[8];
    const float* bng = (const float*)d_in[9];
    const float* bnb = (const float*)d_in[10];
    const float* fcw = (const float*)d_in[11];
    const float* fcb = (const float*)d_in[12];
    float* out = (float*)d_out;

    ushort* H  = (ushort*)d_ws;
    ushort* Z  = H + (size_t)NN * DD;
    ushort* Y1 = Z + (size_t)NN * DD;
    ushort* WP = Y1 + (size_t)NN * DD;
    float* pooled = (float*)(WP + 8 * 16384);
    float* stats  = pooled + (size_t)NL * NG * DD;
    int* deg    = (int*)(stats + 8 * 16 * DD);
    int* rowofs = deg + NN;
    int* part   = rowofs + NN + 1;
    int* cursor = part + 512;
    int* csr    = cursor + NN;

    const int* src = ei;
    const int* dst = ei + NE;
    const int nbN = (NN + 255) / 256;
    const int nbE = (NE + 255) / 256;
    const int nzero = NL * NG * DD + 8 * 16 * DD;

    hipLaunchKernelGGL(k_init, dim3(NN * DD / 8 / 256 + 1), dim3(256), 0, stream,
                       x, H, pooled, nzero, deg, w1, w2, WP);
    hipLaunchKernelGGL(k_hist, dim3(nbE), dim3(256), 0, stream, dst, deg);
    hipLaunchKernelGGL(k_partial, dim3(nbN), dim3(256), 0, stream, deg, part);
    hipLaunchKernelGGL(k_scanpart, dim3(1), dim3(512), 0, stream, part, nbN);
    hipLaunchKernelGGL(k_exscan, dim3(nbN), dim3(256), 0, stream, deg, part, rowofs, cursor);
    hipLaunchKernelGGL(k_fill, dim3(nbE), dim3(256), 0, stream, src, dst, cursor, csr);

    const int gmm = (NN + 63) / 64;   // 1563
    const int ggt = NN / 16;          // 6250
    const int SLOT = 16 * DD;
    for (int i = 0; i < NL; ++i) {
        float* st_mlp = stats + (size_t)(2 * i + 0) * SLOT;
        float* st_out = stats + (size_t)(2 * i + 1) * SLOT;
        const float* st_prev = stats + (size_t)(2 * i - 1) * SLOT;
        float* poolslot = pooled + (size_t)i * NG * DD;
        if (i == 0) {
            hipLaunchKernelGGL((k_gather<false>), dim3(ggt), dim3(256), 0, stream, rowofs, csr, bat, H, Z,
                               (const float*)nullptr, (const float*)nullptr, (const float*)nullptr, poolslot);
        } else {
            hipLaunchKernelGGL((k_gather<true>), dim3(ggt), dim3(256), 0, stream, rowofs, csr, bat, H, Z,
                               st_prev, bng + (size_t)(i - 1) * DD, bnb + (size_t)(i - 1) * DD, poolslot);
        }
        hipLaunchKernelGGL((k_mm<false>), dim3(gmm), dim3(256), 0, stream,
                           Z, WP + (size_t)i * 16384, b1 + (size_t)i * DD,
                           (const float*)nullptr, (const float*)nullptr, (const float*)nullptr,
                           Y1, st_mlp);
        hipLaunchKernelGGL((k_mm<true>), dim3(gmm), dim3(256), 0, stream,
                           Y1, WP + (size_t)(4 + i) * 16384, b2 + (size_t)i * DD,
                           st_mlp, mbg + (size_t)i * DD, mbb + (size_t)i * DD,
                           H, st_out);
    }
    hipLaunchKernelGGL(k_poolread, dim3(NG), dim3(256), 0, stream, bat, H, pooled,
                       stats + (size_t)7 * SLOT, bng + (size_t)3 * DD, bnb + (size_t)3 * DD,
                       fcw, fcb, out);
}